// Round 1
// baseline (6972.866 us; speedup 1.0000x reference)
//
#include <hip/hip_runtime.h>
#include <hip/hip_bf16.h>
#include <math.h>

#define NDIM 512
#define NB   128
#define NMIN 511
#define NMAT 129
#define EPSF 1e-7f

// workspace layout (float offsets)
#define OFF_E   ((size_t)0)                    // 512*512*4 = 1,048,576
#define OFF_WM  ((size_t)1048576)              // 262,144
#define OFF_V   ((size_t)(OFF_WM + 262144))    // 1,024
#define OFF_IPR ((size_t)(OFF_V + 1024))       // 65,536
#define OFF_LPR ((size_t)(OFF_IPR + 65536))    // 128
#define OFF_LD  ((size_t)(OFF_LPR + 128))      // 129
#define OFF_MAT ((size_t)1377792)              // 129 * 262144 (aligned)
#define MAT_STRIDE ((size_t)262144)            // 512*512 floats per matrix (511x511 used)

// ---------- V = softmax(V_compress, axis=1) ----------
__global__ __launch_bounds__(256) void k_V(const float* __restrict__ Vc, float* __restrict__ V) {
  int i = blockIdx.x * 256 + threadIdx.x;
  if (i < NDIM) {
    float v0 = Vc[2*i], v1 = Vc[2*i+1];
    float mx = fmaxf(v0, v1);
    float e0 = expf(v0 - mx), e1 = expf(v1 - mx);
    float s = e0 + e1;
    V[2*i]   = e0 / s;
    V[2*i+1] = e1 / s;
  }
}

// ---------- Wm = sym(tril(sigmoid(W), -1)) ----------
__global__ __launch_bounds__(256) void k_Wm(const float* __restrict__ W, float* __restrict__ Wm) {
  int idx = blockIdx.x * 256 + threadIdx.x;
  int i = idx >> 9, j = idx & 511;
  float v = 0.f;
  if (i > j)      v = 1.f / (1.f + expf(-W[i*NDIM + j]));
  else if (i < j) v = 1.f / (1.f + expf(-W[j*NDIM + i]));
  Wm[idx] = v;
}

// ---------- per-(i,j) 2x2 IPF on E ----------
__global__ __launch_bounds__(256) void k_E(const float* __restrict__ Ec, const float* __restrict__ V,
                                           float* __restrict__ E4) {
  int idx = blockIdx.x * 256 + threadIdx.x;   // i*512 + j
  int i = idx >> 9, j = idx & 511;
  float4 ec = reinterpret_cast<const float4*>(Ec)[idx];
  float e00 = expf(ec.x), e01 = expf(ec.y), e10 = expf(ec.z), e11 = expf(ec.w);
  float s = e00 + e01 + e10 + e11;            // initial normalize: no EPS (matches ref)
  float inv = 1.f / s;
  e00 *= inv; e01 *= inv; e10 *= inv; e11 *= inv;
  float A0 = V[2*i], A1 = V[2*i+1];
  float B0 = V[2*j], B1 = V[2*j+1];
  for (int t = 0; t < 10; ++t) {
    float rm0 = e00 + e01 + EPSF, rm1 = e10 + e11 + EPSF;   // marginals from SAME E
    float cm0 = e00 + e10 + EPSF, cm1 = e01 + e11 + EPSF;
    float f0 = A0 / rm0, f1 = A1 / rm1;
    e00 *= f0; e01 *= f0; e10 *= f1; e11 *= f1;
    float g0 = B0 / cm0, g1 = B1 / cm1;                     // stale col marginal (matches ref)
    e00 *= g0; e10 *= g0; e01 *= g1; e11 *= g1;
    float ss = e00 + e01 + e10 + e11 + EPSF;
    float iv = 1.f / ss;
    e00 *= iv; e01 *= iv; e10 *= iv; e11 *= iv;
  }
  if (i == j) { e00 = 0.f; e01 = 0.f; e10 = 0.f; e11 = 0.f; }
  e00 = fminf(fmaxf(e00, 0.f), 1.f);
  e01 = fminf(fmaxf(e01, 0.f), 1.f);
  e10 = fminf(fmaxf(e10, 0.f), 1.f);
  e11 = fminf(fmaxf(e11, 0.f), 1.f);
  reinterpret_cast<float4*>(E4)[idx] = make_float4(e00, e01, e10, e11);
}

// ---------- Pr, invPr, sum(log Pr) per batch ----------
__global__ __launch_bounds__(256) void k_Pr(const int* __restrict__ x, const float* __restrict__ V,
                                            float* __restrict__ invPr, float* __restrict__ logPr) {
  const int b = blockIdx.x;
  const int tid = threadIdx.x;
  float acc = 0.f;
  for (int ii = tid; ii < NDIM; ii += 256) {
    const int xv = x[b*NDIM + ii];
    const float p = V[2*ii + xv];
    invPr[b*NDIM + ii] = 1.f / p;
    acc += logf(p);
  }
  for (int off = 32; off > 0; off >>= 1) acc += __shfl_down(acc, off, 64);
  __shared__ float sw[4];
  if ((tid & 63) == 0) sw[tid >> 6] = acc;
  __syncthreads();
  if (tid == 0) logPr[b] = sw[0] + sw[1] + sw[2] + sw[3];
}

// ---------- build 511x511 minors: batches b<128 -> Lb, b==128 -> L0 ----------
__global__ __launch_bounds__(512) void k_build(const int* __restrict__ x, const float* __restrict__ E4,
                                               const float* __restrict__ Wm, const float* __restrict__ invPr,
                                               float* __restrict__ Mall) {
  const int b = blockIdx.y;       // 0..128
  const int i = blockIdx.x + 1;   // reference row 1..511
  const int j = threadIdx.x;      // reference col 0..511
  float wp;
  if (b < NB) {
    const int xi = x[b*NDIM + i];
    const int xj = x[b*NDIM + j];
    const float e = E4[(((size_t)i*NDIM + j)*2 + xi)*2 + xj];
    wp = Wm[i*NDIM + j] * e * invPr[b*NDIM + i] * invPr[b*NDIM + j];
  } else {
    wp = Wm[i*NDIM + j];
  }
  float v = wp;
  for (int off = 32; off > 0; off >>= 1) v += __shfl_down(v, off, 64);
  __shared__ float sw[8];
  if ((j & 63) == 0) sw[j >> 6] = v;
  __syncthreads();
  if (j == i) {
    float rs = sw[0]+sw[1]+sw[2]+sw[3]+sw[4]+sw[5]+sw[6]+sw[7];  // full row sum incl. col 0
    Mall[(size_t)b*MAT_STRIDE + (size_t)(i-1)*NDIM + (i-1)] = rs;
  } else if (j >= 1) {
    Mall[(size_t)b*MAT_STRIDE + (size_t)(i-1)*NDIM + (j-1)] = -wp;
  }
}

// ---------- batched blocked LU (no pivoting; matrices are row-diag-dominant) ----------
// One 256-thread workgroup per matrix. nb=32. Panel (transposed) + U row block in LDS.
// Only logdet = sum log|U_kk| is needed -> no L/U write-back; only trailing updates hit memory.
#define LDP 516   // panelT leading dim (floats): 516%4==0 (float4 align), 516%32==4 (bank spread)
#define LDU 484   // rowU leading dim

__global__ __launch_bounds__(256) void k_lu(float* __restrict__ Mall, float* __restrict__ logdets) {
  __shared__ float panelT[32 * LDP];   // [col p][panel-local row i], i in [0, m)
  __shared__ float rowU[32 * LDU];     // [row p][trailing col j], j in [0, mrem)
  const int n = NMIN;
  const int b = blockIdx.x;
  float* __restrict__ M = Mall + (size_t)b * MAT_STRIDE;
  const int tid = threadIdx.x;
  const int tx = tid & 15, ty = tid >> 4;
  float logacc = 0.f;

  for (int k0 = 0; k0 < n; k0 += 32) {
    const int m = n - k0;
    const int w = (m < 32) ? m : 32;
    const int mrem = m - w;

    // load column panel (cols k0..k0+w-1, rows k0..n-1), transposed into LDS
    {
      const int c = tid & 31;
      if (c < w) {
        for (int r = tid >> 5; r < m; r += 8)
          panelT[c*LDP + r] = M[(size_t)(k0+r)*NDIM + (k0+c)];
      }
    }
    __syncthreads();

    // in-LDS panel factorization
    for (int kk = 0; kk < w; ++kk) {
      float piv = panelT[kk*LDP + kk];
      if (tid == 0) logacc += logf(fabsf(piv));
      float invp = 1.f / piv;
      for (int i = kk + 1 + tid; i < m; i += 256) {
        float l = panelT[kk*LDP + i] * invp;
        panelT[kk*LDP + i] = l;
        for (int jc = kk + 1; jc < w; ++jc)
          panelT[jc*LDP + i] -= l * panelT[jc*LDP + kk];
      }
      __syncthreads();
    }

    if (mrem > 0) {   // (mrem>0 implies w==32)
      // load U row block A12 (rows k0..k0+31, cols k0+32..n-1)
      for (int r = 0; r < 32; ++r)
        for (int c = tid; c < mrem; c += 256)
          rowU[r*LDU + c] = M[(size_t)(k0+r)*NDIM + (k0+32+c)];
      __syncthreads();

      // TRSM: U12 = L11^{-1} A12 — columns independent, no barriers inside
      for (int c = tid; c < mrem; c += 256) {
        float u[32];
        #pragma unroll
        for (int r = 0; r < 32; ++r) u[r] = rowU[r*LDU + c];
        #pragma unroll
        for (int kk = 1; kk < 32; ++kk) {
          float acc = u[kk];
          for (int p = 0; p < kk; ++p)
            acc -= panelT[p*LDP + kk] * u[p];   // L11[kk][p]
          u[kk] = acc;
        }
        #pragma unroll
        for (int r = 1; r < 32; ++r) rowU[r*LDU + c] = u[r];
      }
      __syncthreads();

      // trailing update: C -= L21 * U12, 64x64 tiles, 4x4 per thread
      const int nt = (mrem + 63) >> 6;
      for (int ti = 0; ti < nt; ++ti) {
        const int ib = ti*64 + ty*4;
        for (int tj = 0; tj < nt; ++tj) {
          const int jb = tj*64 + tx*4;
          if (ib + 4 <= mrem && jb + 4 <= mrem) {
            float* Cb = M + (size_t)(k0+32+ib)*NDIM + (k0+32+jb);
            float4 c0 = *(float4*)(Cb + 0*NDIM);
            float4 c1 = *(float4*)(Cb + 1*NDIM);
            float4 c2 = *(float4*)(Cb + 2*NDIM);
            float4 c3 = *(float4*)(Cb + 3*NDIM);
            const float* ap = &panelT[32 + ib];
            const float* bp = &rowU[jb];
            #pragma unroll 8
            for (int p = 0; p < 32; ++p) {
              float4 av = *(const float4*)(ap + p*LDP);
              float4 bv = *(const float4*)(bp + p*LDU);
              c0.x -= av.x*bv.x; c0.y -= av.x*bv.y; c0.z -= av.x*bv.z; c0.w -= av.x*bv.w;
              c1.x -= av.y*bv.x; c1.y -= av.y*bv.y; c1.z -= av.y*bv.z; c1.w -= av.y*bv.w;
              c2.x -= av.z*bv.x; c2.y -= av.z*bv.y; c2.z -= av.z*bv.z; c2.w -= av.z*bv.w;
              c3.x -= av.w*bv.x; c3.y -= av.w*bv.y; c3.z -= av.w*bv.z; c3.w -= av.w*bv.w;
            }
            *(float4*)(Cb + 0*NDIM) = c0;
            *(float4*)(Cb + 1*NDIM) = c1;
            *(float4*)(Cb + 2*NDIM) = c2;
            *(float4*)(Cb + 3*NDIM) = c3;
          } else if (ib < mrem && jb < mrem) {
            int rmax = mrem - ib; if (rmax > 4) rmax = 4;
            int cmax = mrem - jb; if (cmax > 4) cmax = 4;
            float* Cb = M + (size_t)(k0+32+ib)*NDIM + (k0+32+jb);
            float creg[4][4];
            for (int r = 0; r < rmax; ++r)
              for (int c = 0; c < cmax; ++c)
                creg[r][c] = Cb[r*NDIM + c];
            for (int p = 0; p < 32; ++p) {
              float a_[4], b_[4];
              for (int r = 0; r < rmax; ++r) a_[r] = panelT[p*LDP + 32 + ib + r];
              for (int c = 0; c < cmax; ++c) b_[c] = rowU[p*LDU + jb + c];
              for (int r = 0; r < rmax; ++r)
                for (int c = 0; c < cmax; ++c)
                  creg[r][c] -= a_[r] * b_[c];
            }
            for (int r = 0; r < rmax; ++r)
              for (int c = 0; c < cmax; ++c)
                Cb[r*NDIM + c] = creg[r][c];
          }
        }
      }
    }
    __syncthreads();   // global C writes visible block-wide before next panel load
  }
  if (tid == 0) logdets[b] = logacc;
}

// ---------- final combine ----------
__global__ void k_final(const float* __restrict__ logPr, const float* __restrict__ logdets,
                        float* __restrict__ out) {
  int t = threadIdx.x;
  if (t < NB) out[t] = logPr[t] + logdets[t] - logdets[NB];
}

extern "C" void kernel_launch(void* const* d_in, const int* in_sizes, int n_in,
                              void* d_out, int out_size, void* d_ws, size_t ws_size,
                              hipStream_t stream) {
  const int*   x  = (const int*)  d_in[0];
  const float* W  = (const float*)d_in[1];
  const float* Vc = (const float*)d_in[2];
  const float* Ec = (const float*)d_in[3];
  float* out = (float*)d_out;
  float* ws  = (float*)d_ws;
  (void)in_sizes; (void)n_in; (void)out_size; (void)ws_size;  // needs ~134.3 MiB of ws

  k_V  <<<2,    256, 0, stream>>>(Vc, ws + OFF_V);
  k_Wm <<<1024, 256, 0, stream>>>(W,  ws + OFF_WM);
  k_E  <<<1024, 256, 0, stream>>>(Ec, ws + OFF_V, ws + OFF_E);
  k_Pr <<<NB,   256, 0, stream>>>(x,  ws + OFF_V, ws + OFF_IPR, ws + OFF_LPR);
  dim3 gb(NMIN, NMAT);
  k_build<<<gb, 512, 0, stream>>>(x, ws + OFF_E, ws + OFF_WM, ws + OFF_IPR, ws + OFF_MAT);
  k_lu <<<NMAT, 256, 0, stream>>>(ws + OFF_MAT, ws + OFF_LD);
  k_final<<<1, 128, 0, stream>>>(ws + OFF_LPR, ws + OFF_LD, out);
}

// Round 2
// 2981.330 us; speedup vs baseline: 2.3388x; 2.3388x over previous
//
#include <hip/hip_runtime.h>
#include <hip/hip_bf16.h>
#include <math.h>

#define NDIM 512
#define NB   128
#define NMAT 129
#define EPSF 1e-7f
#define MS  ((size_t)262144)   // matrix stride (floats) = 512*512
#define LTS ((size_t)32768)    // Lt stride per matrix (floats) = 64*512

// workspace layout (float offsets)
#define OFF_E   ((size_t)0)                    // 1,048,576
#define OFF_WM  ((size_t)1048576)              // 262,144
#define OFF_V   ((size_t)(OFF_WM + 262144))    // 1,024
#define OFF_IPR ((size_t)(OFF_V + 1024))       // 65,536
#define OFF_LPR ((size_t)(OFF_IPR + 65536))    // 128
#define OFF_LD  ((size_t)(OFF_LPR + 128))      // 129 (pad to 1,377,792)
#define OFF_LT  ((size_t)1377792)              // 129*32768 = 4,227,072
#define OFF_MAT ((size_t)(OFF_LT + (size_t)NMAT*LTS))   // 5,604,864; + 33,816,576 -> ~158 MB

// ---------- V = softmax(V_compress, axis=1) ----------
__global__ __launch_bounds__(256) void k_V(const float* __restrict__ Vc, float* __restrict__ V) {
  int i = blockIdx.x * 256 + threadIdx.x;
  if (i < NDIM) {
    float v0 = Vc[2*i], v1 = Vc[2*i+1];
    float mx = fmaxf(v0, v1);
    float e0 = expf(v0 - mx), e1 = expf(v1 - mx);
    float s = e0 + e1;
    V[2*i]   = e0 / s;
    V[2*i+1] = e1 / s;
  }
}

// ---------- Wm = sym(tril(sigmoid(W), -1)) ----------
__global__ __launch_bounds__(256) void k_Wm(const float* __restrict__ W, float* __restrict__ Wm) {
  int idx = blockIdx.x * 256 + threadIdx.x;
  int i = idx >> 9, j = idx & 511;
  float v = 0.f;
  if (i > j)      v = 1.f / (1.f + expf(-W[i*NDIM + j]));
  else if (i < j) v = 1.f / (1.f + expf(-W[j*NDIM + i]));
  Wm[idx] = v;
}

// ---------- per-(i,j) 2x2 IPF on E ----------
__global__ __launch_bounds__(256) void k_E(const float* __restrict__ Ec, const float* __restrict__ V,
                                           float* __restrict__ E4) {
  int idx = blockIdx.x * 256 + threadIdx.x;   // i*512 + j
  int i = idx >> 9, j = idx & 511;
  float4 ec = reinterpret_cast<const float4*>(Ec)[idx];
  float e00 = expf(ec.x), e01 = expf(ec.y), e10 = expf(ec.z), e11 = expf(ec.w);
  float s = e00 + e01 + e10 + e11;
  float inv = 1.f / s;
  e00 *= inv; e01 *= inv; e10 *= inv; e11 *= inv;
  float A0 = V[2*i], A1 = V[2*i+1];
  float B0 = V[2*j], B1 = V[2*j+1];
  for (int t = 0; t < 10; ++t) {
    float rm0 = e00 + e01 + EPSF, rm1 = e10 + e11 + EPSF;
    float cm0 = e00 + e10 + EPSF, cm1 = e01 + e11 + EPSF;
    float f0 = A0 / rm0, f1 = A1 / rm1;
    e00 *= f0; e01 *= f0; e10 *= f1; e11 *= f1;
    float g0 = B0 / cm0, g1 = B1 / cm1;
    e00 *= g0; e10 *= g0; e01 *= g1; e11 *= g1;
    float ss = e00 + e01 + e10 + e11 + EPSF;
    float iv = 1.f / ss;
    e00 *= iv; e01 *= iv; e10 *= iv; e11 *= iv;
  }
  if (i == j) { e00 = 0.f; e01 = 0.f; e10 = 0.f; e11 = 0.f; }
  e00 = fminf(fmaxf(e00, 0.f), 1.f);
  e01 = fminf(fmaxf(e01, 0.f), 1.f);
  e10 = fminf(fmaxf(e10, 0.f), 1.f);
  e11 = fminf(fmaxf(e11, 0.f), 1.f);
  reinterpret_cast<float4*>(E4)[idx] = make_float4(e00, e01, e10, e11);
}

// ---------- Pr, invPr, sum(log Pr) per batch ----------
__global__ __launch_bounds__(256) void k_Pr(const int* __restrict__ x, const float* __restrict__ V,
                                            float* __restrict__ invPr, float* __restrict__ logPr) {
  const int b = blockIdx.x;
  const int tid = threadIdx.x;
  float acc = 0.f;
  for (int ii = tid; ii < NDIM; ii += 256) {
    const int xv = x[b*NDIM + ii];
    const float p = V[2*ii + xv];
    invPr[b*NDIM + ii] = 1.f / p;
    acc += logf(p);
  }
  for (int off = 32; off > 0; off >>= 1) acc += __shfl_down(acc, off, 64);
  __shared__ float sw[4];
  if ((tid & 63) == 0) sw[tid >> 6] = acc;
  __syncthreads();
  if (tid == 0) logPr[b] = sw[0] + sw[1] + sw[2] + sw[3];
}

// ---------- build 511x511 minors (rows/cols 0..510 of padded 512 matrix) ----------
__global__ __launch_bounds__(512) void k_build(const int* __restrict__ x, const float* __restrict__ E4,
                                               const float* __restrict__ Wm, const float* __restrict__ invPr,
                                               float* __restrict__ Mall) {
  const int b = blockIdx.y;       // 0..128
  const int i = blockIdx.x + 1;   // reference row 1..511
  const int j = threadIdx.x;      // reference col 0..511
  float wp;
  if (b < NB) {
    const int xi = x[b*NDIM + i];
    const int xj = x[b*NDIM + j];
    const float e = E4[(((size_t)i*NDIM + j)*2 + xi)*2 + xj];
    wp = Wm[i*NDIM + j] * e * invPr[b*NDIM + i] * invPr[b*NDIM + j];
  } else {
    wp = Wm[i*NDIM + j];
  }
  float v = wp;
  for (int off = 32; off > 0; off >>= 1) v += __shfl_down(v, off, 64);
  __shared__ float sw[8];
  if ((j & 63) == 0) sw[j >> 6] = v;
  __syncthreads();
  if (j == i) {
    float rs = sw[0]+sw[1]+sw[2]+sw[3]+sw[4]+sw[5]+sw[6]+sw[7];
    Mall[(size_t)b*MS + (size_t)(i-1)*NDIM + (i-1)] = rs;
  } else if (j >= 1) {
    Mall[(size_t)b*MS + (size_t)(i-1)*NDIM + (j-1)] = -wp;
  }
}

// ---------- pad row/col 511 with identity ----------
__global__ __launch_bounds__(512) void k_pad(float* __restrict__ Mall) {
  const int b = blockIdx.x;
  float* M = Mall + (size_t)b*MS;
  const int t = threadIdx.x;
  M[(size_t)511*NDIM + t] = (t == 511) ? 1.f : 0.f;
  if (t < 511) M[(size_t)t*NDIM + 511] = 0.f;
}

// ---------- panel factorization (64 cols), rows-in-registers, 2 rows/thread ----------
// Writes panel TRANSPOSED to Lt: Lt[c*512 + r] = panel(row r, col c). Accumulates logdet.
__global__ __launch_bounds__(256) void k_panel(float* __restrict__ Mall, float* __restrict__ Lt,
                                               float* __restrict__ logdets, int k0) {
  const int b = blockIdx.x;
  float* __restrict__ M = Mall + (size_t)b*MS;
  float* __restrict__ L = Lt + (size_t)b*LTS;
  const int t = threadIdx.x;
  const int m = NDIM - k0;          // 512,448,...,64
  __shared__ float pivrow[2][72];
  float a0[64], a1[64];
  const bool h0 = (t < m);
  const bool h1 = (t + 256 < m);
  if (h0) {
    const float* row = M + (size_t)(k0+t)*NDIM + k0;
    #pragma unroll
    for (int c4 = 0; c4 < 16; ++c4) {
      float4 v = *(const float4*)(row + c4*4);
      a0[c4*4+0]=v.x; a0[c4*4+1]=v.y; a0[c4*4+2]=v.z; a0[c4*4+3]=v.w;
    }
  }
  if (h1) {
    const float* row = M + (size_t)(k0+t+256)*NDIM + k0;
    #pragma unroll
    for (int c4 = 0; c4 < 16; ++c4) {
      float4 v = *(const float4*)(row + c4*4);
      a1[c4*4+0]=v.x; a1[c4*4+1]=v.y; a1[c4*4+2]=v.z; a1[c4*4+3]=v.w;
    }
  }
  float logp = 0.f;
  #pragma unroll
  for (int kk = 0; kk < 64; ++kk) {
    float* pb = pivrow[kk & 1];
    if (t == kk) {
      #pragma unroll
      for (int c4 = 0; c4 < 16; ++c4)
        *(float4*)(pb + c4*4) = make_float4(a0[c4*4+0], a0[c4*4+1], a0[c4*4+2], a0[c4*4+3]);
    }
    __syncthreads();
    const float piv = pb[kk];
    const float invp = 1.0f / piv;
    if (t == kk) logp = logf(fabsf(piv));
    const bool u0 = h0 && (t > kk);
    const bool u1 = h1;                       // t+256 > kk always
    float l0 = u0 ? a0[kk]*invp : 0.f;
    float l1 = u1 ? a1[kk]*invp : 0.f;
    if (u0) a0[kk] = l0;
    if (u1) a1[kk] = l1;
    #pragma unroll
    for (int c4 = 0; c4 < 16; ++c4) {
      if (c4*4 + 3 > kk) {                    // static after unroll
        const float4 pr = *(const float4*)(pb + c4*4);
        if (c4*4+0 > kk) { a0[c4*4+0] -= l0*pr.x; a1[c4*4+0] -= l1*pr.x; }
        if (c4*4+1 > kk) { a0[c4*4+1] -= l0*pr.y; a1[c4*4+1] -= l1*pr.y; }
        if (c4*4+2 > kk) { a0[c4*4+2] -= l0*pr.z; a1[c4*4+2] -= l1*pr.z; }
        if (c4*4+3 > kk) { a0[c4*4+3] -= l0*pr.w; a1[c4*4+3] -= l1*pr.w; }
      }
    }
  }
  // write transposed panel: Lt[c][r]; lanes over r -> coalesced
  if (h0) {
    #pragma unroll
    for (int c = 0; c < 64; ++c) L[(size_t)c*NDIM + t] = a0[c];
  }
  if (h1) {
    #pragma unroll
    for (int c = 0; c < 64; ++c) L[(size_t)c*NDIM + (t+256)] = a1[c];
  }
  // logdet partial: pivots live in threads 0..63 (a0[t] = U[t][t] recorded via logp)
  if (t < 64) {
    float v = logp;
    for (int off = 32; off > 0; off >>= 1) v += __shfl_down(v, off, 64);
    if (t == 0) logdets[b] = (k0 == 0) ? v : (logdets[b] + v);
  }
}

// ---------- TRSM: U12 = L11^{-1} A12, column-parallel, L11 broadcast from LDS ----------
__global__ __launch_bounds__(128) void k_u(float* __restrict__ Mall, const float* __restrict__ Lt,
                                           int k0, int mrem) {
  const int b = blockIdx.x;
  float* __restrict__ M = Mall + (size_t)b*MS;
  const float* __restrict__ L = Lt + (size_t)b*LTS;
  __shared__ float Ls[64][68];     // Ls[p][kk] = L[kk][p]
  const int tid = threadIdx.x;
  #pragma unroll
  for (int i = 0; i < 8; ++i) {
    int q = tid + 128*i;           // 1024 float4
    int p = q >> 4, f = q & 15;
    *(float4*)&Ls[p][f*4] = *(const float4*)&L[(size_t)p*NDIM + f*4];
  }
  __syncthreads();
  const int c = blockIdx.y*128 + tid;
  if (c < mrem) {
    const int col = k0 + 64 + c;
    float u[64];
    #pragma unroll
    for (int r = 0; r < 64; ++r) u[r] = M[(size_t)(k0+r)*NDIM + col];
    #pragma unroll
    for (int p = 0; p < 63; ++p) {
      const float lv = u[p];
      #pragma unroll
      for (int kk = p+1; kk < 64; ++kk)
        u[kk] -= Ls[p][kk] * lv;
    }
    #pragma unroll
    for (int r = 1; r < 64; ++r) M[(size_t)(k0+r)*NDIM + col] = u[r];
  }
}

// ---------- trailing update: C -= L21 * U12, 64x64 tile, 4x4/thread ----------
__global__ __launch_bounds__(256, 4) void k_gemm(float* __restrict__ Mall, const float* __restrict__ Lt,
                                                 int k0) {
  const int b = blockIdx.x;
  float* __restrict__ M = Mall + (size_t)b*MS;
  const float* __restrict__ L = Lt + (size_t)b*LTS;
  __shared__ float As[64][68];     // As[p][r] = L21[r][p]
  __shared__ float Bs[64][68];     // Bs[p][c] = U12[p][c]
  const int tid = threadIdx.x;
  const int tx = tid & 15, ty = tid >> 4;
  const int rowbase = 64 + blockIdx.y*64;   // panel-local row of C tile
  const int colbase = 64 + blockIdx.z*64;   // panel-local col
  #pragma unroll
  for (int i = 0; i < 4; ++i) {
    int q = tid + 256*i;           // 1024 float4
    int p = q >> 4, f = q & 15;
    *(float4*)&As[p][f*4] = *(const float4*)&L[(size_t)p*NDIM + rowbase + f*4];
    *(float4*)&Bs[p][f*4] = *(const float4*)&M[(size_t)(k0+p)*NDIM + (k0+colbase) + f*4];
  }
  float* Crow = M + (size_t)(k0+rowbase+ty*4)*NDIM + (k0+colbase+tx*4);
  float4 c0 = *(float4*)(Crow + 0*NDIM);
  float4 c1 = *(float4*)(Crow + 1*NDIM);
  float4 c2 = *(float4*)(Crow + 2*NDIM);
  float4 c3 = *(float4*)(Crow + 3*NDIM);
  __syncthreads();
  #pragma unroll
  for (int p = 0; p < 64; ++p) {
    const float4 av = *(const float4*)&As[p][ty*4];
    const float4 bv = *(const float4*)&Bs[p][tx*4];
    c0.x -= av.x*bv.x; c0.y -= av.x*bv.y; c0.z -= av.x*bv.z; c0.w -= av.x*bv.w;
    c1.x -= av.y*bv.x; c1.y -= av.y*bv.y; c1.z -= av.y*bv.z; c1.w -= av.y*bv.w;
    c2.x -= av.z*bv.x; c2.y -= av.z*bv.y; c2.z -= av.z*bv.z; c2.w -= av.z*bv.w;
    c3.x -= av.w*bv.x; c3.y -= av.w*bv.y; c3.z -= av.w*bv.z; c3.w -= av.w*bv.w;
  }
  *(float4*)(Crow + 0*NDIM) = c0;
  *(float4*)(Crow + 1*NDIM) = c1;
  *(float4*)(Crow + 2*NDIM) = c2;
  *(float4*)(Crow + 3*NDIM) = c3;
}

// ---------- final combine ----------
__global__ void k_final(const float* __restrict__ logPr, const float* __restrict__ logdets,
                        float* __restrict__ out) {
  int t = threadIdx.x;
  if (t < NB) out[t] = logPr[t] + logdets[t] - logdets[NB];
}

extern "C" void kernel_launch(void* const* d_in, const int* in_sizes, int n_in,
                              void* d_out, int out_size, void* d_ws, size_t ws_size,
                              hipStream_t stream) {
  const int*   x  = (const int*)  d_in[0];
  const float* W  = (const float*)d_in[1];
  const float* Vc = (const float*)d_in[2];
  const float* Ec = (const float*)d_in[3];
  float* out = (float*)d_out;
  float* ws  = (float*)d_ws;
  (void)in_sizes; (void)n_in; (void)out_size; (void)ws_size;  // needs ~158 MiB of ws

  float* Mat = ws + OFF_MAT;
  float* Lt  = ws + OFF_LT;
  float* Ld  = ws + OFF_LD;

  k_V  <<<2,    256, 0, stream>>>(Vc, ws + OFF_V);
  k_Wm <<<1024, 256, 0, stream>>>(W,  ws + OFF_WM);
  k_E  <<<1024, 256, 0, stream>>>(Ec, ws + OFF_V, ws + OFF_E);
  k_Pr <<<NB,   256, 0, stream>>>(x,  ws + OFF_V, ws + OFF_IPR, ws + OFF_LPR);
  dim3 gb(511, NMAT);
  k_build<<<gb, 512, 0, stream>>>(x, ws + OFF_E, ws + OFF_WM, ws + OFF_IPR, Mat);
  k_pad<<<NMAT, 512, 0, stream>>>(Mat);

  for (int s = 0; s < 8; ++s) {
    const int k0 = s*64;
    const int mrem = NDIM - k0 - 64;
    k_panel<<<NMAT, 256, 0, stream>>>(Mat, Lt, Ld, k0);
    if (mrem > 0) {
      dim3 gu(NMAT, (mrem + 127)/128);
      k_u<<<gu, 128, 0, stream>>>(Mat, Lt, k0, mrem);
      const int nt = mrem/64;
      dim3 gg(NMAT, nt, nt);
      k_gemm<<<gg, 256, 0, stream>>>(Mat, Lt, k0);
    }
  }
  k_final<<<1, 128, 0, stream>>>(ws + OFF_LPR, Ld, out);
}

// Round 3
// 796.802 us; speedup vs baseline: 8.7511x; 3.7416x over previous
//
#include <hip/hip_runtime.h>
#include <hip/hip_bf16.h>
#include <math.h>

#define NDIM 512
#define NB   128
#define NMAT 129
#define EPSF 1e-7f
#define MS  ((size_t)262144)   // matrix stride (floats) = 512*512
#define LTS ((size_t)32768)    // Lt stride per matrix (floats) = 64*512

// workspace layout (float offsets)
#define OFF_E   ((size_t)0)                    // 1,048,576
#define OFF_WM  ((size_t)1048576)              // 262,144
#define OFF_V   ((size_t)(OFF_WM + 262144))    // 1,024
#define OFF_IPR ((size_t)(OFF_V + 1024))       // 65,536
#define OFF_LPR ((size_t)(OFF_IPR + 65536))    // 128
#define OFF_LD  ((size_t)(OFF_LPR + 128))      // 129 (pad to 1,377,792)
#define OFF_LT  ((size_t)1377792)              // 129*32768 = 4,227,072
#define OFF_MAT ((size_t)(OFF_LT + (size_t)NMAT*LTS))   // ~158 MB total

// ---------- V = softmax(V_compress, axis=1) ----------
__global__ __launch_bounds__(256) void k_V(const float* __restrict__ Vc, float* __restrict__ V) {
  int i = blockIdx.x * 256 + threadIdx.x;
  if (i < NDIM) {
    float v0 = Vc[2*i], v1 = Vc[2*i+1];
    float mx = fmaxf(v0, v1);
    float e0 = expf(v0 - mx), e1 = expf(v1 - mx);
    float s = e0 + e1;
    V[2*i]   = e0 / s;
    V[2*i+1] = e1 / s;
  }
}

// ---------- Wm = sym(tril(sigmoid(W), -1)) ----------
__global__ __launch_bounds__(256) void k_Wm(const float* __restrict__ W, float* __restrict__ Wm) {
  int idx = blockIdx.x * 256 + threadIdx.x;
  int i = idx >> 9, j = idx & 511;
  float v = 0.f;
  if (i > j)      v = 1.f / (1.f + expf(-W[i*NDIM + j]));
  else if (i < j) v = 1.f / (1.f + expf(-W[j*NDIM + i]));
  Wm[idx] = v;
}

// ---------- per-(i,j) 2x2 IPF on E ----------
__global__ __launch_bounds__(256) void k_E(const float* __restrict__ Ec, const float* __restrict__ V,
                                           float* __restrict__ E4) {
  int idx = blockIdx.x * 256 + threadIdx.x;   // i*512 + j
  int i = idx >> 9, j = idx & 511;
  float4 ec = reinterpret_cast<const float4*>(Ec)[idx];
  float e00 = expf(ec.x), e01 = expf(ec.y), e10 = expf(ec.z), e11 = expf(ec.w);
  float s = e00 + e01 + e10 + e11;
  float inv = 1.f / s;
  e00 *= inv; e01 *= inv; e10 *= inv; e11 *= inv;
  float A0 = V[2*i], A1 = V[2*i+1];
  float B0 = V[2*j], B1 = V[2*j+1];
  for (int t = 0; t < 10; ++t) {
    float rm0 = e00 + e01 + EPSF, rm1 = e10 + e11 + EPSF;
    float cm0 = e00 + e10 + EPSF, cm1 = e01 + e11 + EPSF;
    float f0 = A0 / rm0, f1 = A1 / rm1;
    e00 *= f0; e01 *= f0; e10 *= f1; e11 *= f1;
    float g0 = B0 / cm0, g1 = B1 / cm1;
    e00 *= g0; e10 *= g0; e01 *= g1; e11 *= g1;
    float ss = e00 + e01 + e10 + e11 + EPSF;
    float iv = 1.f / ss;
    e00 *= iv; e01 *= iv; e10 *= iv; e11 *= iv;
  }
  if (i == j) { e00 = 0.f; e01 = 0.f; e10 = 0.f; e11 = 0.f; }
  e00 = fminf(fmaxf(e00, 0.f), 1.f);
  e01 = fminf(fmaxf(e01, 0.f), 1.f);
  e10 = fminf(fmaxf(e10, 0.f), 1.f);
  e11 = fminf(fmaxf(e11, 0.f), 1.f);
  reinterpret_cast<float4*>(E4)[idx] = make_float4(e00, e01, e10, e11);
}

// ---------- Pr, invPr, sum(log Pr) per batch ----------
__global__ __launch_bounds__(256) void k_Pr(const int* __restrict__ x, const float* __restrict__ V,
                                            float* __restrict__ invPr, float* __restrict__ logPr) {
  const int b = blockIdx.x;
  const int tid = threadIdx.x;
  float acc = 0.f;
  for (int ii = tid; ii < NDIM; ii += 256) {
    const int xv = x[b*NDIM + ii];
    const float p = V[2*ii + xv];
    invPr[b*NDIM + ii] = 1.f / p;
    acc += logf(p);
  }
  for (int off = 32; off > 0; off >>= 1) acc += __shfl_down(acc, off, 64);
  __shared__ float sw[4];
  if ((tid & 63) == 0) sw[tid >> 6] = acc;
  __syncthreads();
  if (tid == 0) logPr[b] = sw[0] + sw[1] + sw[2] + sw[3];
}

// ---------- build 511x511 minors (rows/cols 0..510 of padded 512 matrix) ----------
__global__ __launch_bounds__(512) void k_build(const int* __restrict__ x, const float* __restrict__ E4,
                                               const float* __restrict__ Wm, const float* __restrict__ invPr,
                                               float* __restrict__ Mall) {
  const int b = blockIdx.y;       // 0..128
  const int i = blockIdx.x + 1;   // reference row 1..511
  const int j = threadIdx.x;      // reference col 0..511
  float wp;
  if (b < NB) {
    const int xi = x[b*NDIM + i];
    const int xj = x[b*NDIM + j];
    const float e = E4[(((size_t)i*NDIM + j)*2 + xi)*2 + xj];
    wp = Wm[i*NDIM + j] * e * invPr[b*NDIM + i] * invPr[b*NDIM + j];
  } else {
    wp = Wm[i*NDIM + j];
  }
  float v = wp;
  for (int off = 32; off > 0; off >>= 1) v += __shfl_down(v, off, 64);
  __shared__ float sw[8];
  if ((j & 63) == 0) sw[j >> 6] = v;
  __syncthreads();
  if (j == i) {
    float rs = sw[0]+sw[1]+sw[2]+sw[3]+sw[4]+sw[5]+sw[6]+sw[7];
    Mall[(size_t)b*MS + (size_t)(i-1)*NDIM + (i-1)] = rs;
  } else if (j >= 1) {
    Mall[(size_t)b*MS + (size_t)(i-1)*NDIM + (j-1)] = -wp;
  }
}

// ---------- pad row/col 511 with identity ----------
__global__ __launch_bounds__(512) void k_pad(float* __restrict__ Mall) {
  const int b = blockIdx.x;
  float* M = Mall + (size_t)b*MS;
  const int t = threadIdx.x;
  M[(size_t)511*NDIM + t] = (t == 511) ? 1.f : 0.f;
  if (t < 511) M[(size_t)t*NDIM + 511] = 0.f;
}

// ---------- panel factorization: template-recursive steps, indices all static ----------
// 512 threads, 1 row/thread, a[64] guaranteed in VGPRs (every access compile-time indexed).
template<int KK>
struct PanelStep {
  static __device__ __forceinline__ void run(float (&a)[64], float (*pivrow)[72],
                                             int t, int m, float& logp) {
    float* pb = pivrow[KK & 1];
    if (t == KK) {
      #pragma unroll
      for (int c = 0; c < 16; ++c)
        *(float4*)(pb + c*4) = make_float4(a[c*4], a[c*4+1], a[c*4+2], a[c*4+3]);
      pb[64] = 1.0f / a[KK];          // pivot reciprocal, computed once
      logp += logf(fabsf(a[KK]));
    }
    __syncthreads();
    if (t > KK && t < m) {
      const float l = a[KK] * pb[64];
      a[KK] = l;
      #pragma unroll
      for (int c = KK + 1; c < 64; ++c)
        a[c] -= l * pb[c];
    }
    PanelStep<KK + 1>::run(a, pivrow, t, m, logp);
  }
};
template<>
struct PanelStep<64> {
  static __device__ __forceinline__ void run(float (&)[64], float (*)[72], int, int, float&) {}
};

__global__ __launch_bounds__(512) void k_panel(float* __restrict__ Mall, float* __restrict__ Lt,
                                               float* __restrict__ logdets, int k0) {
  const int b = blockIdx.x;
  float* __restrict__ M = Mall + (size_t)b*MS;
  float* __restrict__ L = Lt + (size_t)b*LTS;
  const int t = threadIdx.x;
  const int m = NDIM - k0;          // 512,448,...,64
  __shared__ float pivrow[2][72];
  float a[64];
  if (t < m) {
    const float* row = M + (size_t)(k0+t)*NDIM + k0;
    #pragma unroll
    for (int c4 = 0; c4 < 16; ++c4) {
      float4 v = *(const float4*)(row + c4*4);
      a[c4*4+0]=v.x; a[c4*4+1]=v.y; a[c4*4+2]=v.z; a[c4*4+3]=v.w;
    }
  }
  float logp = 0.f;
  PanelStep<0>::run(a, pivrow, t, m, logp);
  // write transposed panel: Lt[c][r]; lanes over r -> coalesced
  if (t < m) {
    #pragma unroll
    for (int c = 0; c < 64; ++c) L[(size_t)c*NDIM + t] = a[c];
  }
  // pivot kk's log lives in thread kk (kk in [0,64) -> wave 0)
  if (t < 64) {
    float v = logp;
    for (int off = 32; off > 0; off >>= 1) v += __shfl_down(v, off, 64);
    if (t == 0) logdets[b] = (k0 == 0) ? v : (logdets[b] + v);
  }
}

// ---------- TRSM: U12 = L11^{-1} A12, column-parallel, L11 broadcast from LDS ----------
__global__ __launch_bounds__(128) void k_u(float* __restrict__ Mall, const float* __restrict__ Lt,
                                           int k0, int mrem) {
  const int b = blockIdx.x;
  float* __restrict__ M = Mall + (size_t)b*MS;
  const float* __restrict__ L = Lt + (size_t)b*LTS;
  __shared__ float Ls[64][68];     // Ls[p][kk] = L[kk][p]
  const int tid = threadIdx.x;
  #pragma unroll
  for (int i = 0; i < 8; ++i) {
    int q = tid + 128*i;           // 1024 float4
    int p = q >> 4, f = q & 15;
    *(float4*)&Ls[p][f*4] = *(const float4*)&L[(size_t)p*NDIM + f*4];
  }
  __syncthreads();
  const int c = blockIdx.y*128 + tid;
  if (c < mrem) {
    const int col = k0 + 64 + c;
    float u[64];
    #pragma unroll
    for (int r = 0; r < 64; ++r) u[r] = M[(size_t)(k0+r)*NDIM + col];
    #pragma unroll
    for (int p = 0; p < 63; ++p) {
      const float lv = u[p];
      #pragma unroll
      for (int kk = p+1; kk < 64; ++kk)
        u[kk] -= Ls[p][kk] * lv;
    }
    #pragma unroll
    for (int r = 1; r < 64; ++r) M[(size_t)(k0+r)*NDIM + col] = u[r];
  }
}

// ---------- trailing update: C -= L21 * U12, 64x64 tile, 4x4/thread ----------
__global__ __launch_bounds__(256, 4) void k_gemm(float* __restrict__ Mall, const float* __restrict__ Lt,
                                                 int k0) {
  const int b = blockIdx.x;
  float* __restrict__ M = Mall + (size_t)b*MS;
  const float* __restrict__ L = Lt + (size_t)b*LTS;
  __shared__ float As[64][68];     // As[p][r] = L21[r][p]
  __shared__ float Bs[64][68];     // Bs[p][c] = U12[p][c]
  const int tid = threadIdx.x;
  const int tx = tid & 15, ty = tid >> 4;
  const int rowbase = 64 + blockIdx.y*64;   // panel-local row of C tile
  const int colbase = 64 + blockIdx.z*64;   // panel-local col
  #pragma unroll
  for (int i = 0; i < 4; ++i) {
    int q = tid + 256*i;           // 1024 float4
    int p = q >> 4, f = q & 15;
    *(float4*)&As[p][f*4] = *(const float4*)&L[(size_t)p*NDIM + rowbase + f*4];
    *(float4*)&Bs[p][f*4] = *(const float4*)&M[(size_t)(k0+p)*NDIM + (k0+colbase) + f*4];
  }
  float* Crow = M + (size_t)(k0+rowbase+ty*4)*NDIM + (k0+colbase+tx*4);
  float4 c0 = *(float4*)(Crow + 0*NDIM);
  float4 c1 = *(float4*)(Crow + 1*NDIM);
  float4 c2 = *(float4*)(Crow + 2*NDIM);
  float4 c3 = *(float4*)(Crow + 3*NDIM);
  __syncthreads();
  #pragma unroll
  for (int p = 0; p < 64; ++p) {
    const float4 av = *(const float4*)&As[p][ty*4];
    const float4 bv = *(const float4*)&Bs[p][tx*4];
    c0.x -= av.x*bv.x; c0.y -= av.x*bv.y; c0.z -= av.x*bv.z; c0.w -= av.x*bv.w;
    c1.x -= av.y*bv.x; c1.y -= av.y*bv.y; c1.z -= av.y*bv.z; c1.w -= av.y*bv.w;
    c2.x -= av.z*bv.x; c2.y -= av.z*bv.y; c2.z -= av.z*bv.z; c2.w -= av.z*bv.w;
    c3.x -= av.w*bv.x; c3.y -= av.w*bv.y; c3.z -= av.w*bv.z; c3.w -= av.w*bv.w;
  }
  *(float4*)(Crow + 0*NDIM) = c0;
  *(float4*)(Crow + 1*NDIM) = c1;
  *(float4*)(Crow + 2*NDIM) = c2;
  *(float4*)(Crow + 3*NDIM) = c3;
}

// ---------- final combine ----------
__global__ void k_final(const float* __restrict__ logPr, const float* __restrict__ logdets,
                        float* __restrict__ out) {
  int t = threadIdx.x;
  if (t < NB) out[t] = logPr[t] + logdets[t] - logdets[NB];
}

extern "C" void kernel_launch(void* const* d_in, const int* in_sizes, int n_in,
                              void* d_out, int out_size, void* d_ws, size_t ws_size,
                              hipStream_t stream) {
  const int*   x  = (const int*)  d_in[0];
  const float* W  = (const float*)d_in[1];
  const float* Vc = (const float*)d_in[2];
  const float* Ec = (const float*)d_in[3];
  float* out = (float*)d_out;
  float* ws  = (float*)d_ws;
  (void)in_sizes; (void)n_in; (void)out_size; (void)ws_size;  // needs ~158 MiB of ws

  float* Mat = ws + OFF_MAT;
  float* Lt  = ws + OFF_LT;
  float* Ld  = ws + OFF_LD;

  k_V  <<<2,    256, 0, stream>>>(Vc, ws + OFF_V);
  k_Wm <<<1024, 256, 0, stream>>>(W,  ws + OFF_WM);
  k_E  <<<1024, 256, 0, stream>>>(Ec, ws + OFF_V, ws + OFF_E);
  k_Pr <<<NB,   256, 0, stream>>>(x,  ws + OFF_V, ws + OFF_IPR, ws + OFF_LPR);
  dim3 gb(511, NMAT);
  k_build<<<gb, 512, 0, stream>>>(x, ws + OFF_E, ws + OFF_WM, ws + OFF_IPR, Mat);
  k_pad<<<NMAT, 512, 0, stream>>>(Mat);

  for (int s = 0; s < 8; ++s) {
    const int k0 = s*64;
    const int mrem = NDIM - k0 - 64;
    k_panel<<<NMAT, 512, 0, stream>>>(Mat, Lt, Ld, k0);
    if (mrem > 0) {
      dim3 gu(NMAT, (mrem + 127)/128);
      k_u<<<gu, 128, 0, stream>>>(Mat, Lt, k0, mrem);
      const int nt = mrem/64;
      dim3 gg(NMAT, nt, nt);
      k_gemm<<<gg, 256, 0, stream>>>(Mat, Lt, k0);
    }
  }
  k_final<<<1, 128, 0, stream>>>(ws + OFF_LPR, Ld, out);
}

// Round 4
// 732.942 us; speedup vs baseline: 9.5135x; 1.0871x over previous
//
#include <hip/hip_runtime.h>
#include <hip/hip_bf16.h>
#include <math.h>

#define NDIM 512
#define NB   128
#define NMAT 129
#define EPSF 1e-7f
#define MS  ((size_t)262144)   // matrix stride (floats) = 512*512
#define LTS ((size_t)32768)    // Lt stride per matrix (floats) = 64*512
#define PSTR ((size_t)524288)  // E2 plane stride (floats) = 512*512*2

// workspace layout (float offsets)
#define OFF_E   ((size_t)0)                    // 2 planes * 524288 = 1,048,576
#define OFF_WM  ((size_t)1048576)              // 262,144
#define OFF_V   ((size_t)(OFF_WM + 262144))    // 1,024
#define OFF_IPR ((size_t)(OFF_V + 1024))       // 65,536
#define OFF_LPR ((size_t)(OFF_IPR + 65536))    // 128
#define OFF_LD  ((size_t)(OFF_LPR + 128))      // 129 (pad to 1,377,792)
#define OFF_LT  ((size_t)1377792)              // 129*32768 = 4,227,072
#define OFF_MAT ((size_t)(OFF_LT + (size_t)NMAT*LTS))   // ~158 MB total

// ---------- V = softmax(V_compress, axis=1) ----------
__global__ __launch_bounds__(256) void k_V(const float* __restrict__ Vc, float* __restrict__ V) {
  int i = blockIdx.x * 256 + threadIdx.x;
  if (i < NDIM) {
    float v0 = Vc[2*i], v1 = Vc[2*i+1];
    float mx = fmaxf(v0, v1);
    float e0 = expf(v0 - mx), e1 = expf(v1 - mx);
    float s = e0 + e1;
    V[2*i]   = e0 / s;
    V[2*i+1] = e1 / s;
  }
}

// ---------- Wm = sym(tril(sigmoid(W), -1)) ----------
__global__ __launch_bounds__(256) void k_Wm(const float* __restrict__ W, float* __restrict__ Wm) {
  int idx = blockIdx.x * 256 + threadIdx.x;
  int i = idx >> 9, j = idx & 511;
  float v = 0.f;
  if (i > j)      v = 1.f / (1.f + expf(-W[i*NDIM + j]));
  else if (i < j) v = 1.f / (1.f + expf(-W[j*NDIM + i]));
  Wm[idx] = v;
}

// ---------- per-(i,j) 2x2 IPF on E; output as xi-planes, xj interleaved ----------
// E2[xi][(i*512+j)*2 + xj]
__global__ __launch_bounds__(256) void k_E(const float* __restrict__ Ec, const float* __restrict__ V,
                                           float* __restrict__ E2) {
  int idx = blockIdx.x * 256 + threadIdx.x;   // i*512 + j
  int i = idx >> 9, j = idx & 511;
  float4 ec = reinterpret_cast<const float4*>(Ec)[idx];
  float e00 = expf(ec.x), e01 = expf(ec.y), e10 = expf(ec.z), e11 = expf(ec.w);
  float s = e00 + e01 + e10 + e11;
  float inv = 1.f / s;
  e00 *= inv; e01 *= inv; e10 *= inv; e11 *= inv;
  float A0 = V[2*i], A1 = V[2*i+1];
  float B0 = V[2*j], B1 = V[2*j+1];
  for (int t = 0; t < 10; ++t) {
    float rm0 = e00 + e01 + EPSF, rm1 = e10 + e11 + EPSF;
    float cm0 = e00 + e10 + EPSF, cm1 = e01 + e11 + EPSF;
    float f0 = A0 / rm0, f1 = A1 / rm1;
    e00 *= f0; e01 *= f0; e10 *= f1; e11 *= f1;
    float g0 = B0 / cm0, g1 = B1 / cm1;
    e00 *= g0; e10 *= g0; e01 *= g1; e11 *= g1;
    float ss = e00 + e01 + e10 + e11 + EPSF;
    float iv = 1.f / ss;
    e00 *= iv; e01 *= iv; e10 *= iv; e11 *= iv;
  }
  if (i == j) { e00 = 0.f; e01 = 0.f; e10 = 0.f; e11 = 0.f; }
  e00 = fminf(fmaxf(e00, 0.f), 1.f);
  e01 = fminf(fmaxf(e01, 0.f), 1.f);
  e10 = fminf(fmaxf(e10, 0.f), 1.f);
  e11 = fminf(fmaxf(e11, 0.f), 1.f);
  reinterpret_cast<float2*>(E2)[idx]               = make_float2(e00, e01);  // plane xi=0
  reinterpret_cast<float2*>(E2 + PSTR)[idx]        = make_float2(e10, e11);  // plane xi=1
}

// ---------- Pr, invPr, sum(log Pr) per batch ----------
__global__ __launch_bounds__(256) void k_Pr(const int* __restrict__ x, const float* __restrict__ V,
                                            float* __restrict__ invPr, float* __restrict__ logPr) {
  const int b = blockIdx.x;
  const int tid = threadIdx.x;
  float acc = 0.f;
  for (int ii = tid; ii < NDIM; ii += 256) {
    const int xv = x[b*NDIM + ii];
    const float p = V[2*ii + xv];
    invPr[b*NDIM + ii] = 1.f / p;
    acc += logf(p);
  }
  for (int off = 32; off > 0; off >>= 1) acc += __shfl_down(acc, off, 64);
  __shared__ float sw[4];
  if ((tid & 63) == 0) sw[tid >> 6] = acc;
  __syncthreads();
  if (tid == 0) logPr[b] = sw[0] + sw[1] + sw[2] + sw[3];
}

// ---------- build 511x511 minors; grid = (b fast, i slow) for L2 locality ----------
__global__ __launch_bounds__(512) void k_build(const int* __restrict__ x, const float* __restrict__ E2,
                                               const float* __restrict__ Wm, const float* __restrict__ invPr,
                                               float* __restrict__ Mall) {
  const int b = blockIdx.x;       // 0..128 (fast)
  const int i = blockIdx.y + 1;   // reference row 1..511 (slow)
  const int j = threadIdx.x;      // reference col 0..511
  float wp;
  if (b < NB) {
    const int xi = x[b*NDIM + i];           // block-uniform
    const int xj = x[b*NDIM + j];
    const float e = E2[(size_t)xi*PSTR + (size_t)(((i<<9) + j)*2 + xj)];
    wp = Wm[i*NDIM + j] * e * invPr[b*NDIM + i] * invPr[b*NDIM + j];
  } else {
    wp = Wm[i*NDIM + j];
  }
  float v = wp;
  for (int off = 32; off > 0; off >>= 1) v += __shfl_down(v, off, 64);
  __shared__ float sw[8];
  if ((j & 63) == 0) sw[j >> 6] = v;
  __syncthreads();
  float* Mrow = Mall + (size_t)b*MS + (size_t)(i-1)*NDIM;
  if (j == i) {
    float rs = sw[0]+sw[1]+sw[2]+sw[3]+sw[4]+sw[5]+sw[6]+sw[7];
    Mrow[i-1] = rs;
  } else if (j >= 1) {
    Mrow[j-1] = -wp;
  } else {
    Mrow[511] = 0.f;    // pad column (j == 0 thread)
  }
}

// ---------- pad row 511 with identity ----------
__global__ __launch_bounds__(512) void k_pad(float* __restrict__ Mall) {
  const int b = blockIdx.x;
  float* M = Mall + (size_t)b*MS;
  const int t = threadIdx.x;
  M[(size_t)511*NDIM + t] = (t == 511) ? 1.f : 0.f;
}

// ---------- panel factorization: template-recursive steps, indices all static ----------
template<int KK>
struct PanelStep {
  static __device__ __forceinline__ void run(float (&a)[64], float (*pivrow)[72],
                                             int t, int m, float& logp) {
    float* pb = pivrow[KK & 1];
    if (t == KK) {
      #pragma unroll
      for (int c = 0; c < 16; ++c)
        *(float4*)(pb + c*4) = make_float4(a[c*4], a[c*4+1], a[c*4+2], a[c*4+3]);
      pb[64] = 1.0f / a[KK];          // pivot reciprocal, computed once
      logp += logf(fabsf(a[KK]));
    }
    __syncthreads();
    if (t > KK && t < m) {
      const float l = a[KK] * pb[64];
      a[KK] = l;
      #pragma unroll
      for (int c = KK + 1; c < 64; ++c)
        a[c] -= l * pb[c];
    }
    PanelStep<KK + 1>::run(a, pivrow, t, m, logp);
  }
};
template<>
struct PanelStep<64> {
  static __device__ __forceinline__ void run(float (&)[64], float (*)[72], int, int, float&) {}
};

__global__ __launch_bounds__(512) void k_panel(float* __restrict__ Mall, float* __restrict__ Lt,
                                               float* __restrict__ logdets, int k0) {
  const int b = blockIdx.x;
  float* __restrict__ M = Mall + (size_t)b*MS;
  float* __restrict__ L = Lt + (size_t)b*LTS;
  const int t = threadIdx.x;
  const int m = NDIM - k0;          // 512,448,...,64
  __shared__ float pivrow[2][72];
  float a[64];
  if (t < m) {
    const float* row = M + (size_t)(k0+t)*NDIM + k0;
    #pragma unroll
    for (int c4 = 0; c4 < 16; ++c4) {
      float4 v = *(const float4*)(row + c4*4);
      a[c4*4+0]=v.x; a[c4*4+1]=v.y; a[c4*4+2]=v.z; a[c4*4+3]=v.w;
    }
  }
  float logp = 0.f;
  PanelStep<0>::run(a, pivrow, t, m, logp);
  // write transposed panel: Lt[c][r]; lanes over r -> coalesced
  if (t < m) {
    #pragma unroll
    for (int c = 0; c < 64; ++c) L[(size_t)c*NDIM + t] = a[c];
  }
  if (t < 64) {
    float v = logp;
    for (int off = 32; off > 0; off >>= 1) v += __shfl_down(v, off, 64);
    if (t == 0) logdets[b] = (k0 == 0) ? v : (logdets[b] + v);
  }
}

// ---------- TRSM: U12 = L11^{-1} A12, column-parallel, L11 broadcast from LDS ----------
__global__ __launch_bounds__(128) void k_u(float* __restrict__ Mall, const float* __restrict__ Lt,
                                           int k0, int mrem) {
  const int b = blockIdx.x;
  float* __restrict__ M = Mall + (size_t)b*MS;
  const float* __restrict__ L = Lt + (size_t)b*LTS;
  __shared__ float Ls[64][68];     // Ls[p][kk] = L[kk][p]
  const int tid = threadIdx.x;
  #pragma unroll
  for (int i = 0; i < 8; ++i) {
    int q = tid + 128*i;           // 1024 float4
    int p = q >> 4, f = q & 15;
    *(float4*)&Ls[p][f*4] = *(const float4*)&L[(size_t)p*NDIM + f*4];
  }
  __syncthreads();
  const int c = blockIdx.y*128 + tid;
  if (c < mrem) {
    const int col = k0 + 64 + c;
    float u[64];
    #pragma unroll
    for (int r = 0; r < 64; ++r) u[r] = M[(size_t)(k0+r)*NDIM + col];
    #pragma unroll
    for (int p = 0; p < 63; ++p) {
      const float lv = u[p];
      #pragma unroll
      for (int kk = p+1; kk < 64; ++kk)
        u[kk] -= Ls[p][kk] * lv;
    }
    #pragma unroll
    for (int r = 1; r < 64; ++r) M[(size_t)(k0+r)*NDIM + col] = u[r];
  }
}

// ---------- trailing update: C -= L21 * U12, 64x64 tile, 4x4/thread ----------
__global__ __launch_bounds__(256, 4) void k_gemm(float* __restrict__ Mall, const float* __restrict__ Lt,
                                                 int k0) {
  const int b = blockIdx.x;
  float* __restrict__ M = Mall + (size_t)b*MS;
  const float* __restrict__ L = Lt + (size_t)b*LTS;
  __shared__ float As[64][68];     // As[p][r] = L21[r][p]
  __shared__ float Bs[64][68];     // Bs[p][c] = U12[p][c]
  const int tid = threadIdx.x;
  const int tx = tid & 15, ty = tid >> 4;
  const int rowbase = 64 + blockIdx.y*64;   // panel-local row of C tile
  const int colbase = 64 + blockIdx.z*64;   // panel-local col
  #pragma unroll
  for (int i = 0; i < 4; ++i) {
    int q = tid + 256*i;           // 1024 float4
    int p = q >> 4, f = q & 15;
    *(float4*)&As[p][f*4] = *(const float4*)&L[(size_t)p*NDIM + rowbase + f*4];
    *(float4*)&Bs[p][f*4] = *(const float4*)&M[(size_t)(k0+p)*NDIM + (k0+colbase) + f*4];
  }
  float* Crow = M + (size_t)(k0+rowbase+ty*4)*NDIM + (k0+colbase+tx*4);
  float4 c0 = *(float4*)(Crow + 0*NDIM);
  float4 c1 = *(float4*)(Crow + 1*NDIM);
  float4 c2 = *(float4*)(Crow + 2*NDIM);
  float4 c3 = *(float4*)(Crow + 3*NDIM);
  __syncthreads();
  #pragma unroll
  for (int p = 0; p < 64; ++p) {
    const float4 av = *(const float4*)&As[p][ty*4];
    const float4 bv = *(const float4*)&Bs[p][tx*4];
    c0.x -= av.x*bv.x; c0.y -= av.x*bv.y; c0.z -= av.x*bv.z; c0.w -= av.x*bv.w;
    c1.x -= av.y*bv.x; c1.y -= av.y*bv.y; c1.z -= av.y*bv.z; c1.w -= av.y*bv.w;
    c2.x -= av.z*bv.x; c2.y -= av.z*bv.y; c2.z -= av.z*bv.z; c2.w -= av.z*bv.w;
    c3.x -= av.w*bv.x; c3.y -= av.w*bv.y; c3.z -= av.w*bv.z; c3.w -= av.w*bv.w;
  }
  *(float4*)(Crow + 0*NDIM) = c0;
  *(float4*)(Crow + 1*NDIM) = c1;
  *(float4*)(Crow + 2*NDIM) = c2;
  *(float4*)(Crow + 3*NDIM) = c3;
}

// ---------- final combine ----------
__global__ void k_final(const float* __restrict__ logPr, const float* __restrict__ logdets,
                        float* __restrict__ out) {
  int t = threadIdx.x;
  if (t < NB) out[t] = logPr[t] + logdets[t] - logdets[NB];
}

extern "C" void kernel_launch(void* const* d_in, const int* in_sizes, int n_in,
                              void* d_out, int out_size, void* d_ws, size_t ws_size,
                              hipStream_t stream) {
  const int*   x  = (const int*)  d_in[0];
  const float* W  = (const float*)d_in[1];
  const float* Vc = (const float*)d_in[2];
  const float* Ec = (const float*)d_in[3];
  float* out = (float*)d_out;
  float* ws  = (float*)d_ws;
  (void)in_sizes; (void)n_in; (void)out_size; (void)ws_size;  // needs ~158 MiB of ws

  float* Mat = ws + OFF_MAT;
  float* Lt  = ws + OFF_LT;
  float* Ld  = ws + OFF_LD;

  k_V  <<<2,    256, 0, stream>>>(Vc, ws + OFF_V);
  k_Wm <<<1024, 256, 0, stream>>>(W,  ws + OFF_WM);
  k_E  <<<1024, 256, 0, stream>>>(Ec, ws + OFF_V, ws + OFF_E);
  k_Pr <<<NB,   256, 0, stream>>>(x,  ws + OFF_V, ws + OFF_IPR, ws + OFF_LPR);
  dim3 gb(NMAT, 511);
  k_build<<<gb, 512, 0, stream>>>(x, ws + OFF_E, ws + OFF_WM, ws + OFF_IPR, Mat);
  k_pad<<<NMAT, 512, 0, stream>>>(Mat);

  for (int s = 0; s < 8; ++s) {
    const int k0 = s*64;
    const int mrem = NDIM - k0 - 64;
    k_panel<<<NMAT, 512, 0, stream>>>(Mat, Lt, Ld, k0);
    if (mrem > 0) {
      dim3 gu(NMAT, (mrem + 127)/128);
      k_u<<<gu, 128, 0, stream>>>(Mat, Lt, k0, mrem);
      const int nt = mrem/64;
      dim3 gg(NMAT, nt, nt);
      k_gemm<<<gg, 256, 0, stream>>>(Mat, Lt, k0);
    }
  }
  k_final<<<1, 128, 0, stream>>>(ws + OFF_LPR, Ld, out);
}